// Round 1
// baseline (445.536 us; speedup 1.0000x reference)
//
#include <hip/hip_runtime.h>
#include <stdint.h>

typedef unsigned short u16;
typedef __bf16 bf16x8 __attribute__((ext_vector_type(8)));
typedef float  f32x4  __attribute__((ext_vector_type(4)));

static constexpr int Bd = 4096;   // batch
static constexpr int Kd = 2048;   // in-features (GEMM K)
static constexpr int Fd = 4096;   // out-features

// Workspace layout (bytes). yr aliases X1+W1 (both dead before GEMM writes).
static constexpr size_t OFF_QX   = 0;                    // u16[4096*2048] bf16 bits
static constexpr size_t OFF_QWT  = 16777216;             // u16[4096*2048] (transposed: [F][K])
static constexpr size_t OFF_X1   = 33554432;             // float[4096*2048]  (H2 @ x, unnormalized)
static constexpr size_t OFF_W1   = 67108864;             // float[2048*4096]  (w @ H1, unnormalized)
static constexpr size_t OFF_YR   = 33554432;             // float[4096*4096]  aliases X1,W1
static constexpr size_t OFF_SCAL = 100663296;            // 2x u32 (max|X1|, max|W1| as float bits)

// ---------------- FWHT helpers (register-resident, fully unrolled) ----------------
__device__ __forceinline__ void fwht16(float* v) {
#pragma unroll
  for (int b = 1; b < 16; b <<= 1) {
#pragma unroll
    for (int i = 0; i < 16; ++i) {
      if (!(i & b)) { float a = v[i]; float c = v[i | b]; v[i] = a + c; v[i | b] = a - c; }
    }
  }
}

__device__ __forceinline__ void fwht64(float* v) {
#pragma unroll
  for (int b = 1; b < 64; b <<= 1) {
#pragma unroll
    for (int i = 0; i < 64; ++i) {
      if (!(i & b)) { float a = v[i]; float c = v[i | b]; v[i] = a + c; v[i | b] = a - c; }
    }
  }
}

__global__ void init_scal(unsigned int* s) {
  if (threadIdx.x < 2) s[threadIdx.x] = 0u;  // ws is poisoned 0xAA every launch
}

// ---------------- Flavor A: H64 along a strided row-group (column-direction stage) ----
// rows(r) = blockIdx.y*bmult + r*rstride, r in [0,64); col = blockIdx.x*256 + tid.
// Each thread owns one full column of the 64-row group in registers. No LDS for data.
template<bool DOMAX, bool DOBIAS>
__global__ __launch_bounds__(256) void col_fwht64(const float* __restrict__ in,
                                                  float* __restrict__ out,
                                                  int C, int rstride, int bmult,
                                                  unsigned int* gmax,
                                                  const float* __restrict__ bias) {
  __shared__ float red[4];
  const int t = threadIdx.x;
  const int col = blockIdx.x * 256 + t;
  const int base = blockIdx.y * bmult;
  float v[64];
#pragma unroll
  for (int r = 0; r < 64; ++r)
    v[r] = in[(size_t)(base + r * rstride) * C + col];
  fwht64(v);
  if (DOBIAS) {
    float bv = bias[col];
#pragma unroll
    for (int r = 0; r < 64; ++r) v[r] += bv;
  }
#pragma unroll
  for (int r = 0; r < 64; ++r)
    out[(size_t)(base + r * rstride) * C + col] = v[r];
  if (DOMAX) {
    float m = 0.f;
#pragma unroll
    for (int r = 0; r < 64; ++r) m = fmaxf(m, fabsf(v[r]));
#pragma unroll
    for (int off = 32; off > 0; off >>= 1) m = fmaxf(m, __shfl_down(m, off));
    if ((t & 63) == 0) red[t >> 6] = m;
    __syncthreads();
    if (t == 0) {
      m = fmaxf(fmaxf(red[0], red[1]), fmaxf(red[2], red[3]));
      atomicMax(gmax, __float_as_uint(m));  // m >= 0: float bits monotone
    }
  }
}

// ---------------- Flavor B: full FWHT-4096 along a contiguous row ----------------
// 3 register FWHT16 rounds over bit-groups {11..8},{7..4},{3..0}; padded LDS between.
template<bool DOMAX>
__global__ __launch_bounds__(256) void row_fwht4096(const float* __restrict__ in,
                                                    float* __restrict__ out,
                                                    unsigned int* gmax) {
  __shared__ float s[4224];  // 4096 + pad (addr = e + (e>>5)) -> <=2-way bank aliasing (free)
  __shared__ float red[4];
  const int t = threadIdx.x;
  const size_t rowoff = (size_t)blockIdx.x * 4096;
  float v[16];
  // P1: v[j] = e = (j<<8)|t  (coalesced dword loads); FWHT over bits 11..8
#pragma unroll
  for (int j = 0; j < 16; ++j) v[j] = in[rowoff + ((j << 8) | t)];
  fwht16(v);
#pragma unroll
  for (int j = 0; j < 16; ++j) { int e = (j << 8) | t; s[e + (e >> 5)] = v[j]; }
  __syncthreads();
  // P2: e = (t>>4)<<8 | j<<4 | (t&15); FWHT over bits 7..4
#pragma unroll
  for (int j = 0; j < 16; ++j) { int e = ((t >> 4) << 8) | (j << 4) | (t & 15); v[j] = s[e + (e >> 5)]; }
  fwht16(v);
#pragma unroll
  for (int j = 0; j < 16; ++j) { int e = ((t >> 4) << 8) | (j << 4) | (t & 15); s[e + (e >> 5)] = v[j]; }
  __syncthreads();
  // P3: e = t<<4 | j; FWHT over bits 3..0
#pragma unroll
  for (int j = 0; j < 16; ++j) { int e = (t << 4) | j; v[j] = s[e + (e >> 5)]; }
  fwht16(v);
#pragma unroll
  for (int i = 0; i < 4; ++i) {
    float4 o = make_float4(v[4 * i], v[4 * i + 1], v[4 * i + 2], v[4 * i + 3]);
    *(float4*)&out[rowoff + (t << 4) + 4 * i] = o;
  }
  if (DOMAX) {
    float m = 0.f;
#pragma unroll
    for (int j = 0; j < 16; ++j) m = fmaxf(m, fabsf(v[j]));
#pragma unroll
    for (int off = 32; off > 0; off >>= 1) m = fmaxf(m, __shfl_down(m, off));
    if ((t & 63) == 0) red[t >> 6] = m;
    __syncthreads();
    if (t == 0) {
      m = fmaxf(fmaxf(red[0], red[1]), fmaxf(red[2], red[3]));
      atomicMax(gmax, __float_as_uint(m));
    }
  }
}

// ---------------- Stochastic quantization (mirrors reference rounding path) --------
__device__ __forceinline__ float quant1(float X1, float nz, float s) {
  float xr = X1 * 0.015625f;         // /64, exact
  float xs = xr / s;                 // IEEE f32 divide, same as numpy
  float f  = floorf(xs);
  float q  = f + ((nz < (xs - f)) ? 1.0f : 0.0f);
  return fminf(fmaxf(q, -127.0f), 127.0f);
}
__device__ __forceinline__ u16 f32_to_bf16_exact(float q) {
  return (u16)(__float_as_uint(q) >> 16);  // |q|<=127 integer: low 16 mantissa bits are 0
}

__global__ __launch_bounds__(256) void quant_x_kern(const float4* __restrict__ X1,
                                                    const float4* __restrict__ nz,
                                                    u16* __restrict__ qx,
                                                    const unsigned int* __restrict__ scal) {
  size_t g = (size_t)blockIdx.x * 256 + threadIdx.x;
  float Mx = __uint_as_float(scal[0]);
  float s = (Mx * 0.015625f) / 127.0f;   // same rounding as ref: (max/64)/127
  float4 xv = X1[g];
  float4 nv = nz[g];
  unsigned int lo = (unsigned int)f32_to_bf16_exact(quant1(xv.x, nv.x, s)) |
                    ((unsigned int)f32_to_bf16_exact(quant1(xv.y, nv.y, s)) << 16);
  unsigned int hi = (unsigned int)f32_to_bf16_exact(quant1(xv.z, nv.z, s)) |
                    ((unsigned int)f32_to_bf16_exact(quant1(xv.w, nv.w, s)) << 16);
  *(uint2*)(qx + 4 * g) = make_uint2(lo, hi);
}

// Quantize W1 [K,F] and write transposed bf16 [F,K] via LDS 64x64 tile.
__global__ __launch_bounds__(256) void quant_w_t(const float* __restrict__ W1,
                                                 const float* __restrict__ nz,
                                                 u16* __restrict__ qwT,
                                                 const unsigned int* __restrict__ scal) {
  __shared__ float tile[64][65];
  const int t = threadIdx.x;
  const int c = t & 63, r4 = t >> 6;
  const int k0 = blockIdx.x * 64;   // over K=2048
  const int n0 = blockIdx.y * 64;   // over F=4096
  float Mw = __uint_as_float(scal[1]);
  float s = (Mw * 0.015625f) / 127.0f;
#pragma unroll
  for (int i = 0; i < 16; ++i) {
    int k = r4 + i * 4;
    size_t idx = (size_t)(k0 + k) * Fd + n0 + c;
    tile[k][c] = quant1(W1[idx], nz[idx], s);
  }
  __syncthreads();
#pragma unroll
  for (int i = 0; i < 16; ++i) {
    int n = r4 + i * 4;
    qwT[(size_t)(n0 + n) * Kd + k0 + c] = f32_to_bf16_exact(tile[c][n]);
  }
}

// ---------------- GEMM: yr = (qx @ qw) * sx*sw/4096  (m97 structure, bf16 MFMA) -----
__device__ __forceinline__ void async16(const void* g, void* l) {
  __builtin_amdgcn_global_load_lds((__attribute__((address_space(1))) void*)(g),
                                   (__attribute__((address_space(3))) void*)(l),
                                   16, 0, 0);
}
__device__ __forceinline__ bf16x8 ld_frag(const u16* p) {
  uint4 u = *(const uint4*)p;
  return __builtin_bit_cast(bf16x8, u);
}

__global__ __launch_bounds__(256) void gemm_bt(const u16* __restrict__ A,   // [4096,2048] bf16 bits
                                               const u16* __restrict__ Bt,  // [4096,2048] bf16 bits
                                               float* __restrict__ C,       // [4096,4096] f32
                                               const unsigned int* __restrict__ scal) {
  __shared__ __align__(16) u16 As[128 * 64];
  __shared__ __align__(16) u16 Bs[128 * 64];
  const int t = threadIdx.x;
  const int w = t >> 6, l = t & 63;
  const int l15 = l & 15, quad = l >> 4;
  const int m0 = blockIdx.x * 128, n0 = blockIdx.y * 128;
  const int mw = (w & 1) * 64, nw = (w >> 1) * 64;
  f32x4 acc[4][4] = {};

  for (int kg = 0; kg < Kd; kg += 64) {
#pragma unroll
    for (int i = 0; i < 4; ++i) {
      const int c = w * 4 + i;                 // 16 chunks of 1KB each
      const int row = c * 8 + (l >> 3);
      const int cole = (l & 7) * 8;
      async16(A + (size_t)(m0 + row) * Kd + kg + cole, As + c * 512);
      async16(Bt + (size_t)(n0 + row) * Kd + kg + cole, Bs + c * 512);
    }
    __syncthreads();
#pragma unroll
    for (int kk = 0; kk < 64; kk += 32) {
      bf16x8 af[4], bfv[4];
#pragma unroll
      for (int mi = 0; mi < 4; ++mi)
        af[mi] = ld_frag(As + (mw + mi * 16 + l15) * 64 + kk + quad * 8);
#pragma unroll
      for (int ni = 0; ni < 4; ++ni)
        bfv[ni] = ld_frag(Bs + (nw + ni * 16 + l15) * 64 + kk + quad * 8);
#pragma unroll
      for (int mi = 0; mi < 4; ++mi)
#pragma unroll
        for (int ni = 0; ni < 4; ++ni)
          acc[mi][ni] = __builtin_amdgcn_mfma_f32_16x16x32_bf16(af[mi], bfv[ni], acc[mi][ni], 0, 0, 0);
    }
    __syncthreads();
  }
  float sx = (__uint_as_float(scal[0]) * 0.015625f) / 127.0f;
  float sw = (__uint_as_float(scal[1]) * 0.015625f) / 127.0f;
  float alpha = sx * sw * (1.0f / 4096.0f);   // dequant + 1/sqrt(n1*n2)
#pragma unroll
  for (int mi = 0; mi < 4; ++mi)
#pragma unroll
    for (int ni = 0; ni < 4; ++ni)
#pragma unroll
      for (int r = 0; r < 4; ++r) {
        int row = m0 + mw + mi * 16 + quad * 4 + r;   // C/D: row=(lane>>4)*4+reg
        int col = n0 + nw + ni * 16 + l15;            //      col=lane&15
        C[(size_t)row * Fd + col] = acc[mi][ni][r] * alpha;
      }
}

// ---------------- Launch ----------------
extern "C" void kernel_launch(void* const* d_in, const int* in_sizes, int n_in,
                              void* d_out, int out_size, void* d_ws, size_t ws_size,
                              hipStream_t stream) {
  (void)in_sizes; (void)n_in; (void)out_size; (void)ws_size;
  const float* x       = (const float*)d_in[0];  // [4096,2048]
  const float* w       = (const float*)d_in[1];  // [2048,4096]
  const float* bias    = (const float*)d_in[2];  // [4096]
  const float* noise_x = (const float*)d_in[5];  // [4096,2048]
  const float* noise_w = (const float*)d_in[6];  // [2048,4096]
  char* ws = (char*)d_ws;
  u16*   qx   = (u16*)  (ws + OFF_QX);
  u16*   qwT  = (u16*)  (ws + OFF_QWT);
  float* X1   = (float*)(ws + OFF_X1);
  float* W1   = (float*)(ws + OFF_W1);
  float* yr   = (float*)(ws + OFF_YR);
  unsigned int* scal = (unsigned int*)(ws + OFF_SCAL);
  float* out = (float*)d_out;

  init_scal<<<dim3(1), dim3(64), 0, stream>>>(scal);
  // xr (unnormalized): H2 @ x along batch dim = column FWHT4096 in 2 Kronecker stages
  col_fwht64<false, false><<<dim3(Kd / 256, 64), dim3(256), 0, stream>>>(x, X1, Kd, 1, 64, nullptr, nullptr);
  col_fwht64<true,  false><<<dim3(Kd / 256, 64), dim3(256), 0, stream>>>(X1, X1, Kd, 64, 1, scal + 0, nullptr);
  // wr (unnormalized): w @ H1 along feature dim = row FWHT4096
  row_fwht4096<true><<<dim3(Kd), dim3(256), 0, stream>>>(w, W1, scal + 1);
  // stochastic quantization (bf16-exact int grid)
  quant_x_kern<<<dim3((Bd * Kd / 4) / 256), dim3(256), 0, stream>>>((const float4*)X1, (const float4*)noise_x, qx, scal);
  quant_w_t<<<dim3(Kd / 64, Fd / 64), dim3(256), 0, stream>>>(W1, noise_w, qwT, scal);
  // core GEMM (writes yr, aliasing dead X1/W1)
  gemm_bt<<<dim3(Bd / 128, Fd / 128), dim3(256), 0, stream>>>(qx, qwT, yr, scal);
  // y = H2 @ yr @ H1 / 4096 (alpha already applied): row FWHT, then 2 column stages
  row_fwht4096<false><<<dim3(Bd), dim3(256), 0, stream>>>(yr, yr, nullptr);
  col_fwht64<false, false><<<dim3(Fd / 256, 64), dim3(256), 0, stream>>>(yr, yr, Fd, 1, 64, nullptr, nullptr);
  col_fwht64<false, true ><<<dim3(Fd / 256, 64), dim3(256), 0, stream>>>(yr, out, Fd, 64, 1, nullptr, bias);
}

// Round 2
// 371.912 us; speedup vs baseline: 1.1980x; 1.1980x over previous
//
#include <hip/hip_runtime.h>
#include <stdint.h>

typedef unsigned short u16;
typedef unsigned int   u32;
typedef int v4i __attribute__((ext_vector_type(4)));

static constexpr int Bd = 4096;   // batch
static constexpr int Kd = 2048;   // in-features (GEMM K)
static constexpr int Fd = 4096;   // out-features

// Workspace layout (bytes). yr (bf16, 32MB) aliases X1+W1 (dead before GEMM writes).
static constexpr size_t OFF_QX   = 0;          // i8 [4096*2048]            (8 MB)
static constexpr size_t OFF_QWT  = 8388608;    // i8 [4096*2048] transposed (8 MB)
static constexpr size_t OFF_X1   = 16777216;   // f32[4096*2048]            (32 MB)
static constexpr size_t OFF_W1   = 50331648;   // f32[2048*4096]            (32 MB)
static constexpr size_t OFF_YR   = 16777216;   // bf16[4096*4096] aliases X1/W1 (32 MB)
static constexpr size_t OFF_SCAL = 83886080;   // 2x u32 (max|X1|, max|W1| as float bits)

// ---------------- FWHT helpers (register-resident, fully unrolled) ----------------
__device__ __forceinline__ void fwht16(float* v) {
#pragma unroll
  for (int b = 1; b < 16; b <<= 1) {
#pragma unroll
    for (int i = 0; i < 16; ++i) {
      if (!(i & b)) { float a = v[i]; float c = v[i | b]; v[i] = a + c; v[i | b] = a - c; }
    }
  }
}
__device__ __forceinline__ void fwht64(float* v) {
#pragma unroll
  for (int b = 1; b < 64; b <<= 1) {
#pragma unroll
    for (int i = 0; i < 64; ++i) {
      if (!(i & b)) { float a = v[i]; float c = v[i | b]; v[i] = a + c; v[i | b] = a - c; }
    }
  }
}

// ---------------- bf16 pack/unpack ----------------
__device__ __forceinline__ void unpack2(u32 u, float& a, float& b) {
  a = __uint_as_float(u << 16);
  b = __uint_as_float(u & 0xffff0000u);
}
__device__ __forceinline__ u16 bf16_rne(float f) {
  u32 x = __float_as_uint(f);
  return (u16)(((x + 0x7fffu + ((x >> 16) & 1u)) >> 16) & 0xffffu);
}
__device__ __forceinline__ u32 pack2(float a, float b) {
  u32 x = __float_as_uint(a), y = __float_as_uint(b);
  u32 lo = ((x + 0x7fffu + ((x >> 16) & 1u)) >> 16) & 0xffffu;
  u32 hi = (y + 0x7fffu + ((y >> 16) & 1u)) & 0xffff0000u;
  return lo | hi;
}

__global__ void init_scal(u32* s) {
  if (threadIdx.x < 2) s[threadIdx.x] = 0u;  // ws is poisoned 0xAA every launch
}

// ---------------- x-path: H64 along strided row-group, f32 (unchanged from R1) ------
template<bool DOMAX>
__global__ __launch_bounds__(256) void col_fwht64(const float* __restrict__ in,
                                                  float* __restrict__ out,
                                                  int C, int rstride, int bmult,
                                                  u32* gmax) {
  __shared__ float red[4];
  const int t = threadIdx.x;
  const int col = blockIdx.x * 256 + t;
  const int base = blockIdx.y * bmult;
  float v[64];
#pragma unroll
  for (int r = 0; r < 64; ++r)
    v[r] = in[(size_t)(base + r * rstride) * C + col];
  fwht64(v);
#pragma unroll
  for (int r = 0; r < 64; ++r)
    out[(size_t)(base + r * rstride) * C + col] = v[r];
  if (DOMAX) {
    float m = 0.f;
#pragma unroll
    for (int r = 0; r < 64; ++r) m = fmaxf(m, fabsf(v[r]));
#pragma unroll
    for (int off = 32; off > 0; off >>= 1) m = fmaxf(m, __shfl_down(m, off));
    if ((t & 63) == 0) red[t >> 6] = m;
    __syncthreads();
    if (t == 0) {
      m = fmaxf(fmaxf(red[0], red[1]), fmaxf(red[2], red[3]));
      atomicMax(gmax, __float_as_uint(m));
    }
  }
}

// ---------------- w-path: full FWHT-4096 along a row, f32, + max (unchanged) --------
__global__ __launch_bounds__(256) void row_fwht4096_f32(const float* __restrict__ in,
                                                        float* __restrict__ out,
                                                        u32* gmax) {
  __shared__ float s[4224];
  __shared__ float red[4];
  const int t = threadIdx.x;
  const size_t rowoff = (size_t)blockIdx.x * 4096;
  float v[16];
#pragma unroll
  for (int j = 0; j < 16; ++j) v[j] = in[rowoff + ((j << 8) | t)];
  fwht16(v);
#pragma unroll
  for (int j = 0; j < 16; ++j) { int e = (j << 8) | t; s[e + (e >> 5)] = v[j]; }
  __syncthreads();
#pragma unroll
  for (int j = 0; j < 16; ++j) { int e = ((t >> 4) << 8) | (j << 4) | (t & 15); v[j] = s[e + (e >> 5)]; }
  fwht16(v);
#pragma unroll
  for (int j = 0; j < 16; ++j) { int e = ((t >> 4) << 8) | (j << 4) | (t & 15); s[e + (e >> 5)] = v[j]; }
  __syncthreads();
#pragma unroll
  for (int j = 0; j < 16; ++j) { int e = (t << 4) | j; v[j] = s[e + (e >> 5)]; }
  fwht16(v);
#pragma unroll
  for (int i = 0; i < 4; ++i) {
    float4 o = make_float4(v[4 * i], v[4 * i + 1], v[4 * i + 2], v[4 * i + 3]);
    *(float4*)&out[rowoff + (t << 4) + 4 * i] = o;
  }
  float m = 0.f;
#pragma unroll
  for (int j = 0; j < 16; ++j) m = fmaxf(m, fabsf(v[j]));
#pragma unroll
  for (int off = 32; off > 0; off >>= 1) m = fmaxf(m, __shfl_down(m, off));
  if ((t & 63) == 0) red[t >> 6] = m;
  __syncthreads();
  if (t == 0) {
    m = fmaxf(fmaxf(red[0], red[1]), fmaxf(red[2], red[3]));
    atomicMax(gmax, __float_as_uint(m));
  }
}

// ---------------- Stochastic quantization (mirrors reference rounding path) --------
__device__ __forceinline__ float quant1(float X1, float nz, float s) {
  float xr = X1 * 0.015625f;         // /64, exact
  float xs = xr / s;
  float f  = floorf(xs);
  float q  = f + ((nz < (xs - f)) ? 1.0f : 0.0f);
  return fminf(fmaxf(q, -127.0f), 127.0f);
}
__device__ __forceinline__ u32 pk4(float a, float b, float c, float d) {
  return ((u32)(unsigned char)(char)(int)a)        |
         (((u32)(unsigned char)(char)(int)b) << 8) |
         (((u32)(unsigned char)(char)(int)c) << 16)|
         (((u32)(unsigned char)(char)(int)d) << 24);
}

__global__ __launch_bounds__(256) void quant_x_i8(const float4* __restrict__ X1,
                                                  const float4* __restrict__ nz,
                                                  u32* __restrict__ qx,
                                                  const u32* __restrict__ scal) {
  size_t g = (size_t)blockIdx.x * 256 + threadIdx.x;
  float s = (__uint_as_float(scal[0]) * 0.015625f) / 127.0f;
  float4 xv = X1[g];
  float4 nv = nz[g];
  qx[g] = pk4(quant1(xv.x, nv.x, s), quant1(xv.y, nv.y, s),
              quant1(xv.z, nv.z, s), quant1(xv.w, nv.w, s));
}

// Quantize W1 [K,F] and write transposed i8 [F,K] via LDS 64x64 tile, packed u32 stores.
__global__ __launch_bounds__(256) void quant_w_t_i8(const float* __restrict__ W1,
                                                    const float* __restrict__ nz,
                                                    char* __restrict__ qwT,
                                                    const u32* __restrict__ scal) {
  __shared__ float tile[64][65];
  const int t = threadIdx.x;
  const int c = t & 63, r4 = t >> 6;
  const int k0 = blockIdx.x * 64;   // over K=2048
  const int n0 = blockIdx.y * 64;   // over F=4096
  float s = (__uint_as_float(scal[1]) * 0.015625f) / 127.0f;
#pragma unroll
  for (int i = 0; i < 16; ++i) {
    int k = r4 + i * 4;
    size_t idx = (size_t)(k0 + k) * Fd + n0 + c;
    tile[k][c] = quant1(W1[idx], nz[idx], s);
  }
  __syncthreads();
  const int kq = t & 15, nb = t >> 4;
#pragma unroll
  for (int i = 0; i < 4; ++i) {
    int n = nb + 16 * i;
    u32 p = pk4(tile[4 * kq + 0][n], tile[4 * kq + 1][n],
                tile[4 * kq + 2][n], tile[4 * kq + 3][n]);
    *(u32*)(qwT + (size_t)(n0 + n) * Kd + k0 + 4 * kq) = p;
  }
}

// ---------------- GEMM: yr_bf16 = (qx @ qwT^T) * sx*sw/4096, i8 MFMA ----------------
__device__ __forceinline__ void async16(const void* g, void* l) {
  __builtin_amdgcn_global_load_lds((__attribute__((address_space(1))) void*)(g),
                                   (__attribute__((address_space(3))) void*)(l),
                                   16, 0, 0);
}

__global__ __launch_bounds__(256) void gemm_i8(const char* __restrict__ A,   // [4096,2048] i8
                                               const char* __restrict__ Bt,  // [4096,2048] i8
                                               u16* __restrict__ C,          // [4096,4096] bf16
                                               const u32* __restrict__ scal) {
  __shared__ __align__(16) char As[128 * 128];
  __shared__ __align__(16) char Bs[128 * 128];
  const int t = threadIdx.x;
  const int w = t >> 6, l = t & 63;
  const int l15 = l & 15, quad = l >> 4;
  const int xorr = l15 & 7;
  // gm=8 panel swizzle for L2 locality (grid = 1024 1D)
  const int GM = 8, NN = 32, grp = GM * NN;
  int pid = blockIdx.x;
  int gid = pid / grp;
  int mm = gid * GM + (pid % GM);
  int nn = (pid % grp) / GM;
  const int m0 = mm * 128, n0 = nn * 128;
  const int mw = (w & 1) * 64, nw = (w >> 1) * 64;
  v4i acc[4][4] = {};

  // staging indices: chunk c covers rows c*8..c*8+7; lane l -> row c*8+(l>>3), slot bg=l&7.
  // XOR source swizzle: slot (row,bg) holds global byte-group bg ^ (row&7).
  const int srow_lo = l >> 3;               // 0..7
  const int sbg = (l & 7) ^ ((l >> 3) & 7); // swizzled global byte-group

  for (int kg = 0; kg < Kd; kg += 128) {
#pragma unroll
    for (int i = 0; i < 4; ++i) {
      const int c = w * 4 + i;
      const int row = c * 8 + srow_lo;
      async16(A + (size_t)(m0 + row) * Kd + kg + sbg * 16, As + c * 1024);
      async16(Bt + (size_t)(n0 + row) * Kd + kg + sbg * 16, Bs + c * 1024);
    }
    __syncthreads();
#pragma unroll
    for (int kc = 0; kc < 2; ++kc) {
      v4i av[4], bv[4];
#pragma unroll
      for (int mi = 0; mi < 4; ++mi) {
        int row = mw + mi * 16 + l15;
        av[mi] = *(const v4i*)(As + row * 128 + (((kc * 4 + quad) ^ xorr) * 16));
      }
#pragma unroll
      for (int ni = 0; ni < 4; ++ni) {
        int row = nw + ni * 16 + l15;
        bv[ni] = *(const v4i*)(Bs + row * 128 + (((kc * 4 + quad) ^ xorr) * 16));
      }
#pragma unroll
      for (int mi = 0; mi < 4; ++mi)
#pragma unroll
        for (int ni = 0; ni < 4; ++ni)
          acc[mi][ni] = __builtin_amdgcn_mfma_i32_16x16x64_i8(av[mi], bv[ni], acc[mi][ni], 0, 0, 0);
    }
    __syncthreads();
  }
  float sx = (__uint_as_float(scal[0]) * 0.015625f) / 127.0f;
  float sw = (__uint_as_float(scal[1]) * 0.015625f) / 127.0f;
  float alpha = sx * sw * (1.0f / 4096.0f);   // dequant + 1/sqrt(n1*n2)
#pragma unroll
  for (int mi = 0; mi < 4; ++mi)
#pragma unroll
    for (int ni = 0; ni < 4; ++ni)
#pragma unroll
      for (int r = 0; r < 4; ++r) {
        int row = m0 + mw + mi * 16 + quad * 4 + r;   // C/D: row=(lane>>4)*4+reg
        int col = n0 + nw + ni * 16 + l15;            //      col=lane&15
        C[(size_t)row * Fd + col] = bf16_rne((float)acc[mi][ni][r] * alpha);
      }
}

// ---------------- Output row pass: FWHT-4096 per row, bf16 in/out -------------------
__global__ __launch_bounds__(256) void row_fwht4096_bf16(const u16* __restrict__ in,
                                                         u16* __restrict__ out) {
  __shared__ float s[4224];
  const int t = threadIdx.x;
  const size_t ro = (size_t)blockIdx.x * 4096;
  float v[16];
  {
    const uint4* ip = (const uint4*)(in + ro + t * 16);
    uint4 u0 = ip[0], u1 = ip[1];
    unpack2(u0.x, v[0], v[1]);  unpack2(u0.y, v[2], v[3]);
    unpack2(u0.z, v[4], v[5]);  unpack2(u0.w, v[6], v[7]);
    unpack2(u1.x, v[8], v[9]);  unpack2(u1.y, v[10], v[11]);
    unpack2(u1.z, v[12], v[13]); unpack2(u1.w, v[14], v[15]);
  }
  fwht16(v);  // bits 3..0
#pragma unroll
  for (int j = 0; j < 16; ++j) { int e = t * 16 + j; s[e + (e >> 5)] = v[j]; }
  __syncthreads();
#pragma unroll
  for (int j = 0; j < 16; ++j) { int e = ((t >> 4) << 8) | (j << 4) | (t & 15); v[j] = s[e + (e >> 5)]; }
  fwht16(v);  // bits 7..4
#pragma unroll
  for (int j = 0; j < 16; ++j) { int e = ((t >> 4) << 8) | (j << 4) | (t & 15); s[e + (e >> 5)] = v[j]; }
  __syncthreads();
#pragma unroll
  for (int j = 0; j < 16; ++j) { int e = (j << 8) | ((t >> 4) << 4) | (t & 15); v[j] = s[e + (e >> 5)]; }
  fwht16(v);  // bits 11..8
#pragma unroll
  for (int j = 0; j < 16; ++j) { int e = (j << 8) | ((t >> 4) << 4) | (t & 15); s[e + (e >> 5)] = v[j]; }
  __syncthreads();
#pragma unroll
  for (int j = 0; j < 16; ++j) { int e = t * 16 + j; v[j] = s[e + (e >> 5)]; }
  uint4 o0, o1;
  o0.x = pack2(v[0], v[1]);   o0.y = pack2(v[2], v[3]);
  o0.z = pack2(v[4], v[5]);   o0.w = pack2(v[6], v[7]);
  o1.x = pack2(v[8], v[9]);   o1.y = pack2(v[10], v[11]);
  o1.z = pack2(v[12], v[13]); o1.w = pack2(v[14], v[15]);
  uint4* op = (uint4*)(out + ro + t * 16);
  op[0] = o0; op[1] = o1;
}

// ---------------- Output col passes: H64 on row-groups, bf16 column-pairs -----------
template<bool LAST>
__global__ __launch_bounds__(256, 1) void col_fwht64_pair(const u32* __restrict__ in,
                                                          u32* __restrict__ outb,
                                                          float* __restrict__ outf,
                                                          int rstride, int bmult,
                                                          const float* __restrict__ bias) {
  const int t = threadIdx.x;
  const int cp = blockIdx.x * 256 + t;      // column-pair 0..2047
  const int base = blockIdx.y * bmult;
  float va[64], vb[64];
#pragma unroll
  for (int r = 0; r < 64; ++r) {
    u32 u = in[(size_t)(base + r * rstride) * 2048 + cp];
    unpack2(u, va[r], vb[r]);
  }
  fwht64(va);
  fwht64(vb);
  if (LAST) {
    float b0 = bias[2 * cp], b1 = bias[2 * cp + 1];
#pragma unroll
    for (int r = 0; r < 64; ++r) {
      int row = base + r * rstride;
      float2 o = make_float2(va[r] + b0, vb[r] + b1);
      *(float2*)&outf[(size_t)row * 4096 + 2 * cp] = o;
    }
  } else {
#pragma unroll
    for (int r = 0; r < 64; ++r)
      outb[(size_t)(base + r * rstride) * 2048 + cp] = pack2(va[r], vb[r]);
  }
}

// ---------------- Launch ----------------
extern "C" void kernel_launch(void* const* d_in, const int* in_sizes, int n_in,
                              void* d_out, int out_size, void* d_ws, size_t ws_size,
                              hipStream_t stream) {
  (void)in_sizes; (void)n_in; (void)out_size; (void)ws_size;
  const float* x       = (const float*)d_in[0];  // [4096,2048]
  const float* w       = (const float*)d_in[1];  // [2048,4096]
  const float* bias    = (const float*)d_in[2];  // [4096]
  const float* noise_x = (const float*)d_in[5];  // [4096,2048]
  const float* noise_w = (const float*)d_in[6];  // [2048,4096]
  char* ws = (char*)d_ws;
  char*  qx   = (char*) (ws + OFF_QX);
  char*  qwT  = (char*) (ws + OFF_QWT);
  float* X1   = (float*)(ws + OFF_X1);
  float* W1   = (float*)(ws + OFF_W1);
  u16*   yr   = (u16*)  (ws + OFF_YR);
  u32*   scal = (u32*)  (ws + OFF_SCAL);
  float* out  = (float*)d_out;

  init_scal<<<dim3(1), dim3(64), 0, stream>>>(scal);
  // xr (unnormalized): H2 @ x = column FWHT4096 in 2 Kronecker stages (f32)
  col_fwht64<false><<<dim3(Kd / 256, 64), dim3(256), 0, stream>>>(x, X1, Kd, 1, 64, nullptr);
  col_fwht64<true ><<<dim3(Kd / 256, 64), dim3(256), 0, stream>>>(X1, X1, Kd, 64, 1, scal + 0);
  // wr (unnormalized): w @ H1 = row FWHT4096 (f32) + max
  row_fwht4096_f32<<<dim3(Kd), dim3(256), 0, stream>>>(w, W1, scal + 1);
  // stochastic quantization to int8
  quant_x_i8<<<dim3((Bd * Kd / 4) / 256), dim3(256), 0, stream>>>(
      (const float4*)X1, (const float4*)noise_x, (u32*)qx, scal);
  quant_w_t_i8<<<dim3(Kd / 64, Fd / 64), dim3(256), 0, stream>>>(W1, noise_w, qwT, scal);
  // core i8 GEMM -> yr bf16 (aliases dead X1/W1)
  gemm_i8<<<dim3((Bd / 128) * (Fd / 128)), dim3(256), 0, stream>>>(qx, qwT, yr, scal);
  // y = H2 @ yr @ H1 / 4096 (alpha folded into GEMM): row FWHT, then 2 col stages
  row_fwht4096_bf16<<<dim3(Bd), dim3(256), 0, stream>>>(yr, yr);
  col_fwht64_pair<false><<<dim3(Fd / 512, 64), dim3(256), 0, stream>>>(
      (const u32*)yr, (u32*)yr, nullptr, 1, 64, nullptr);
  col_fwht64_pair<true ><<<dim3(Fd / 512, 64), dim3(256), 0, stream>>>(
      (const u32*)yr, nullptr, out, 64, 1, bias);
}

// Round 4
// 370.893 us; speedup vs baseline: 1.2013x; 1.0027x over previous
//
#include <hip/hip_runtime.h>
#include <stdint.h>

typedef unsigned short u16;
typedef unsigned int   u32;
typedef int v4i __attribute__((ext_vector_type(4)));

static constexpr int Bd = 4096;   // batch
static constexpr int Kd = 2048;   // in-features (GEMM K)
static constexpr int Fd = 4096;   // out-features

// Workspace (bytes). yr aliases X1B+W1B (dead before GEMM writes).
static constexpr size_t OFF_QX   = 0;          // i8 [4096*2048]              (8 MB)
static constexpr size_t OFF_QWT  = 8388608;    // i8 [4096*2048] transposed   (8 MB)
static constexpr size_t OFF_X1B  = 16777216;   // u32[4096*1024] bf16 pairs   (16 MB)
static constexpr size_t OFF_W1B  = 33554432;   // u32[2048*2048] bf16 pairs   (16 MB)
static constexpr size_t OFF_YR   = 16777216;   // u16[4096*4096] aliases X1B/W1B (32 MB)
static constexpr size_t OFF_SCAL = 83886080;   // 2x u32 (max|X1|, max|W1| float bits)

// ---------------- FWHT helpers ----------------
__device__ __forceinline__ void fwht16(float* v) {
#pragma unroll
  for (int b = 1; b < 16; b <<= 1) {
#pragma unroll
    for (int i = 0; i < 16; ++i) {
      if (!(i & b)) { float a = v[i]; float c = v[i | b]; v[i] = a + c; v[i | b] = a - c; }
    }
  }
}
__device__ __forceinline__ void fwht64(float* v) {
#pragma unroll
  for (int b = 1; b < 64; b <<= 1) {
#pragma unroll
    for (int i = 0; i < 64; ++i) {
      if (!(i & b)) { float a = v[i]; float c = v[i | b]; v[i] = a + c; v[i | b] = a - c; }
    }
  }
}

// ---------------- bf16 pack/unpack ----------------
__device__ __forceinline__ void unpack2(u32 u, float& a, float& b) {
  a = __uint_as_float(u << 16);
  b = __uint_as_float(u & 0xffff0000u);
}
__device__ __forceinline__ u16 bf16_rne(float f) {
  u32 x = __float_as_uint(f);
  return (u16)(((x + 0x7fffu + ((x >> 16) & 1u)) >> 16) & 0xffffu);
}
__device__ __forceinline__ u32 pack2(float a, float b) {
  u32 x = __float_as_uint(a), y = __float_as_uint(b);
  u32 lo = ((x + 0x7fffu + ((x >> 16) & 1u)) >> 16) & 0xffffu;
  u32 hi = (y + 0x7fffu + ((y >> 16) & 1u)) & 0xffff0000u;
  return lo | hi;
}

// ---------------- x-path stage 1: H64 on consecutive 64-row groups, f32->bf16 -------
__global__ __launch_bounds__(256) void xcol_s1(const float2* __restrict__ x,
                                               u32* __restrict__ X1b,
                                               u32* __restrict__ scal) {
  if (blockIdx.x == 0 && blockIdx.y == 0 && threadIdx.x < 2) scal[threadIdx.x] = 0u;
  const int t = threadIdx.x;
  const int cp = blockIdx.x * 256 + t;       // col pair 0..1023
  const int base = blockIdx.y * 64;
  float va[64], vb[64];
#pragma unroll
  for (int r = 0; r < 64; ++r) {
    float2 xv = x[(size_t)(base + r) * 1024 + cp];
    va[r] = xv.x; vb[r] = xv.y;
  }
  fwht64(va); fwht64(vb);
#pragma unroll
  for (int r = 0; r < 64; ++r)
    X1b[(size_t)(base + r) * 1024 + cp] = pack2(va[r], vb[r]);
}

// ---------------- x-path stage 2: H64 on stride-64 rows, in-place bf16, + max -------
__global__ __launch_bounds__(256) void xcol_s2(u32* __restrict__ X1b,
                                               u32* __restrict__ gmax) {
  __shared__ float red[4];
  const int t = threadIdx.x;
  const int cp = blockIdx.x * 256 + t;
  const int base = blockIdx.y;               // 0..63
  float va[64], vb[64];
#pragma unroll
  for (int r = 0; r < 64; ++r)
    unpack2(X1b[(size_t)(base + r * 64) * 1024 + cp], va[r], vb[r]);
  fwht64(va); fwht64(vb);
  float m = 0.f;
#pragma unroll
  for (int r = 0; r < 64; ++r) {
    X1b[(size_t)(base + r * 64) * 1024 + cp] = pack2(va[r], vb[r]);
    m = fmaxf(m, fmaxf(fabsf(va[r]), fabsf(vb[r])));
  }
#pragma unroll
  for (int off = 32; off > 0; off >>= 1) m = fmaxf(m, __shfl_down(m, off));
  if ((t & 63) == 0) red[t >> 6] = m;
  __syncthreads();
  if (t == 0) {
    m = fmaxf(fmaxf(red[0], red[1]), fmaxf(red[2], red[3]));
    atomicMax(gmax, __float_as_uint(m));
  }
}

// ---------------- w-path: full FWHT-4096 per row, f32 in -> bf16 out, + max --------
__global__ __launch_bounds__(256) void roww_fwht(const float* __restrict__ in,
                                                 u32* __restrict__ W1b,
                                                 u32* __restrict__ gmax) {
  __shared__ float s[4224];
  __shared__ float red[4];
  const int t = threadIdx.x;
  const size_t rowoff = (size_t)blockIdx.x * 4096;
  float v[16];
#pragma unroll
  for (int j = 0; j < 16; ++j) v[j] = in[rowoff + ((j << 8) | t)];
  fwht16(v);
#pragma unroll
  for (int j = 0; j < 16; ++j) { int e = (j << 8) | t; s[e + (e >> 5)] = v[j]; }
  __syncthreads();
#pragma unroll
  for (int j = 0; j < 16; ++j) { int e = ((t >> 4) << 8) | (j << 4) | (t & 15); v[j] = s[e + (e >> 5)]; }
  fwht16(v);
#pragma unroll
  for (int j = 0; j < 16; ++j) { int e = ((t >> 4) << 8) | (j << 4) | (t & 15); s[e + (e >> 5)] = v[j]; }
  __syncthreads();
#pragma unroll
  for (int j = 0; j < 16; ++j) { int e = (t << 4) | j; v[j] = s[e + (e >> 5)]; }
  fwht16(v);
  // store as bf16 pairs: cols t*16 .. t*16+15
  uint4 o0, o1;
  o0.x = pack2(v[0], v[1]);   o0.y = pack2(v[2], v[3]);
  o0.z = pack2(v[4], v[5]);   o0.w = pack2(v[6], v[7]);
  o1.x = pack2(v[8], v[9]);   o1.y = pack2(v[10], v[11]);
  o1.z = pack2(v[12], v[13]); o1.w = pack2(v[14], v[15]);
  uint4* op = (uint4*)(W1b + (size_t)blockIdx.x * 2048 + t * 8);
  op[0] = o0; op[1] = o1;
  float m = 0.f;
#pragma unroll
  for (int j = 0; j < 16; ++j) m = fmaxf(m, fabsf(v[j]));
#pragma unroll
  for (int off = 32; off > 0; off >>= 1) m = fmaxf(m, __shfl_down(m, off));
  if ((t & 63) == 0) red[t >> 6] = m;
  __syncthreads();
  if (t == 0) {
    m = fmaxf(fmaxf(red[0], red[1]), fmaxf(red[2], red[3]));
    atomicMax(gmax, __float_as_uint(m));
  }
}

// ---------------- Stochastic quantization ----------------
__device__ __forceinline__ float quant1(float X1, float nz, float s) {
  float xr = X1 * 0.015625f;         // /64, exact
  float xs = xr / s;
  float f  = floorf(xs);
  float q  = f + ((nz < (xs - f)) ? 1.0f : 0.0f);
  return fminf(fmaxf(q, -127.0f), 127.0f);
}
__device__ __forceinline__ u32 pk4(float a, float b, float c, float d) {
  return ((u32)(unsigned char)(char)(int)a)        |
         (((u32)(unsigned char)(char)(int)b) << 8) |
         (((u32)(unsigned char)(char)(int)c) << 16)|
         (((u32)(unsigned char)(char)(int)d) << 24);
}

__global__ __launch_bounds__(256) void quant_x_i8(const uint4* __restrict__ X1b,
                                                  const float4* __restrict__ nz,
                                                  uint2* __restrict__ qx,
                                                  const u32* __restrict__ scal) {
  size_t g = (size_t)blockIdx.x * 256 + threadIdx.x;
  float s = (__uint_as_float(scal[0]) * 0.015625f) / 127.0f;
  uint4 xv = X1b[g];
  float4 na = nz[2 * g], nb = nz[2 * g + 1];
  float a, b, c, d, e, f, gg, h;
  unpack2(xv.x, a, b);  unpack2(xv.y, c, d);
  unpack2(xv.z, e, f);  unpack2(xv.w, gg, h);
  u32 lo = pk4(quant1(a, na.x, s), quant1(b, na.y, s), quant1(c, na.z, s), quant1(d, na.w, s));
  u32 hi = pk4(quant1(e, nb.x, s), quant1(f, nb.y, s), quant1(gg, nb.z, s), quant1(h, nb.w, s));
  qx[g] = make_uint2(lo, hi);
}

// Quantize W1b [K,F] (bf16 pairs) and write transposed i8 [F,K].
__global__ __launch_bounds__(256) void quant_w_t_i8(const u32* __restrict__ W1b,
                                                    const float2* __restrict__ nz,
                                                    char* __restrict__ qwT,
                                                    const u32* __restrict__ scal) {
  __shared__ float tile[64][65];
  const int t = threadIdx.x;
  const int k0 = blockIdx.x * 64;   // over K=2048
  const int n0 = blockIdx.y * 64;   // over F=4096
  float s = (__uint_as_float(scal[1]) * 0.015625f) / 127.0f;
#pragma unroll
  for (int i = 0; i < 8; ++i) {
    int idx = t + 256 * i;          // 0..2047 over (k, np)
    int k = idx >> 5, np = idx & 31;
    u32 u = W1b[(size_t)(k0 + k) * 2048 + (n0 >> 1) + np];
    float2 nv = nz[(size_t)(k0 + k) * 2048 + (n0 >> 1) + np];
    float a, b; unpack2(u, a, b);
    tile[k][2 * np]     = quant1(a, nv.x, s);
    tile[k][2 * np + 1] = quant1(b, nv.y, s);
  }
  __syncthreads();
  const int kq = t & 15, nb = t >> 4;
#pragma unroll
  for (int i = 0; i < 4; ++i) {
    int n = nb + 16 * i;
    u32 p = pk4(tile[4 * kq + 0][n], tile[4 * kq + 1][n],
                tile[4 * kq + 2][n], tile[4 * kq + 3][n]);
    *(u32*)(qwT + (size_t)(n0 + n) * Kd + k0 + 4 * kq) = p;
  }
}

// ---------------- GEMM (i8 MFMA) + fused Rl/Cl output-rotation epilogue -------------
__device__ __forceinline__ void async16(const void* g, void* l) {
  __builtin_amdgcn_global_load_lds((__attribute__((address_space(1))) void*)(g),
                                   (__attribute__((address_space(3))) void*)(l),
                                   16, 0, 0);
}

__global__ __launch_bounds__(256) void gemm_i8(const char* __restrict__ A,   // [4096,2048] i8
                                               const char* __restrict__ Bt,  // [4096,2048] i8
                                               u16* __restrict__ C,          // [4096,4096] bf16
                                               const u32* __restrict__ scal) {
  __shared__ __align__(16) char As[128 * 128];
  __shared__ __align__(16) char Bs[128 * 128];
  const int t = threadIdx.x;
  const int w = t >> 6, l = t & 63;
  const int l15 = l & 15, quad = l >> 4;
  const int xorr = l15 & 7;
  // gm=8 panel swizzle for L2 locality (grid = 1024 1D)
  const int GM = 8, NN = 32, grp = GM * NN;
  int pid = blockIdx.x;
  int gid = pid / grp;
  int mm = gid * GM + (pid % GM);
  int nn = (pid % grp) / GM;
  const int m0 = mm * 128, n0 = nn * 128;
  const int mw = (w & 1) * 64, nw = (w >> 1) * 64;
  v4i acc[4][4] = {};

  // XOR source swizzle so LDS ds_read_b128 spreads over banks (R2: 0 conflicts)
  const int srow_lo = l >> 3;
  const int sbg = (l & 7) ^ ((l >> 3) & 7);

  for (int kg = 0; kg < Kd; kg += 128) {
#pragma unroll
    for (int i = 0; i < 4; ++i) {
      const int c = w * 4 + i;
      const int row = c * 8 + srow_lo;
      async16(A + (size_t)(m0 + row) * Kd + kg + sbg * 16, As + c * 1024);
      async16(Bt + (size_t)(n0 + row) * Kd + kg + sbg * 16, Bs + c * 1024);
    }
    __syncthreads();
#pragma unroll
    for (int kc = 0; kc < 2; ++kc) {
      v4i av[4], bv[4];
#pragma unroll
      for (int mi = 0; mi < 4; ++mi) {
        int row = mw + mi * 16 + l15;
        av[mi] = *(const v4i*)(As + row * 128 + (((kc * 4 + quad) ^ xorr) * 16));
      }
#pragma unroll
      for (int ni = 0; ni < 4; ++ni) {
        int row = nw + ni * 16 + l15;
        bv[ni] = *(const v4i*)(Bs + row * 128 + (((kc * 4 + quad) ^ xorr) * 16));
      }
#pragma unroll
      for (int mi = 0; mi < 4; ++mi)
#pragma unroll
        for (int ni = 0; ni < 4; ++ni)
          acc[mi][ni] = __builtin_amdgcn_mfma_i32_16x16x64_i8(av[mi], bv[ni], acc[mi][ni], 0, 0, 0);
    }
    __syncthreads();
  }
  float sx = (__uint_as_float(scal[0]) * 0.015625f) / 127.0f;
  float sw = (__uint_as_float(scal[1]) * 0.015625f) / 127.0f;
  float alpha = sx * sw * (1.0f / 4096.0f);

  // ---- fused epilogue: H64 over row-low bits (Rl) and col-low bits (Cl) ----
  // Wave quadrant = aligned 64x64 tile. row6 = mi*16+quad*4+r, col6 = ni*16+l15.
  // Register-resident bits {r, ni, mi} -> plain fwht64 over flat idx (order-free).
  // Lane-resident bits {l15: lane 0-3, quad: lane 4-5} -> 6 shfl_xor butterflies.
  float vals[64];
#pragma unroll
  for (int mi = 0; mi < 4; ++mi)
#pragma unroll
    for (int ni = 0; ni < 4; ++ni)
#pragma unroll
      for (int r = 0; r < 4; ++r)
        vals[mi * 16 + ni * 4 + r] = (float)acc[mi][ni][r] * alpha;
  fwht64(vals);
#pragma unroll
  for (int k = 0; k < 6; ++k) {
    const int mask = 1 << k;
    const int bit = (l >> k) & 1;
#pragma unroll
    for (int i = 0; i < 64; ++i) {
      float p = __shfl_xor(vals[i], mask, 64);
      vals[i] = bit ? (p - vals[i]) : (vals[i] + p);
    }
  }
#pragma unroll
  for (int mi = 0; mi < 4; ++mi)
#pragma unroll
    for (int ni = 0; ni < 4; ++ni)
#pragma unroll
      for (int r = 0; r < 4; ++r) {
        int row = m0 + mw + mi * 16 + quad * 4 + r;
        int col = n0 + nw + ni * 16 + l15;
        C[(size_t)row * Fd + col] = bf16_rne(vals[mi * 16 + ni * 4 + r]);
      }
}

// ---------------- Output pass Ch: H64 over col-high bits, per-row, bf16 in-place ----
__global__ __launch_bounds__(256) void colhigh_fwht(u16* __restrict__ yr) {
  __shared__ u16 sh[4 * 4096];   // 32768 B = 2048 uint4 -> 8 iters of 256 threads
  const int t = threadIdx.x;
  const size_t row0 = (size_t)blockIdx.x * 4;
  uint4* shv = (uint4*)sh;
  const uint4* g = (const uint4*)(yr + row0 * 4096);
#pragma unroll
  for (int i = 0; i < 8; ++i) shv[t + 256 * i] = g[t + 256 * i];
  __syncthreads();
  const int grp = t >> 6, cl = t & 63;
  const u16* shr = sh + grp * 4096;
  float v[64];
#pragma unroll
  for (int ch = 0; ch < 64; ++ch)
    v[ch] = __uint_as_float(((u32)shr[ch * 64 + cl]) << 16);
  fwht64(v);
  __syncthreads();
  u16* shw = sh + grp * 4096;
#pragma unroll
  for (int ch = 0; ch < 64; ++ch)
    shw[ch * 64 + cl] = bf16_rne(v[ch]);
  __syncthreads();
  uint4* go = (uint4*)(yr + row0 * 4096);
#pragma unroll
  for (int i = 0; i < 8; ++i) go[t + 256 * i] = shv[t + 256 * i];
}

// ---------------- Output pass Rh (LAST): H64 over stride-64 rows, +bias, f32 out ----
__global__ __launch_bounds__(256, 1) void rowhigh_last(const u32* __restrict__ in,
                                                       float* __restrict__ outf,
                                                       const float* __restrict__ bias) {
  const int t = threadIdx.x;
  const int cp = blockIdx.x * 256 + t;      // column-pair 0..2047
  const int base = blockIdx.y;              // 0..63
  float va[64], vb[64];
#pragma unroll
  for (int r = 0; r < 64; ++r)
    unpack2(in[(size_t)(base + r * 64) * 2048 + cp], va[r], vb[r]);
  fwht64(va);
  fwht64(vb);
  float b0 = bias[2 * cp], b1 = bias[2 * cp + 1];
#pragma unroll
  for (int r = 0; r < 64; ++r) {
    int row = base + r * 64;
    float2 o = make_float2(va[r] + b0, vb[r] + b1);
    *(float2*)&outf[(size_t)row * 4096 + 2 * cp] = o;
  }
}

// ---------------- Launch ----------------
extern "C" void kernel_launch(void* const* d_in, const int* in_sizes, int n_in,
                              void* d_out, int out_size, void* d_ws, size_t ws_size,
                              hipStream_t stream) {
  (void)in_sizes; (void)n_in; (void)out_size; (void)ws_size;
  const float* x       = (const float*)d_in[0];  // [4096,2048]
  const float* w       = (const float*)d_in[1];  // [2048,4096]
  const float* bias    = (const float*)d_in[2];  // [4096]
  const float* noise_x = (const float*)d_in[5];  // [4096,2048]
  const float* noise_w = (const float*)d_in[6];  // [2048,4096]
  char* ws = (char*)d_ws;
  char* qx   = (char*)(ws + OFF_QX);
  char* qwT  = (char*)(ws + OFF_QWT);
  u32*  X1b  = (u32*) (ws + OFF_X1B);
  u32*  W1b  = (u32*) (ws + OFF_W1B);
  u16*  yr   = (u16*) (ws + OFF_YR);
  u32*  scal = (u32*) (ws + OFF_SCAL);
  float* out = (float*)d_out;

  // x rotation: H2 @ x (2 stages, bf16 intermediate); stage1 also zeroes scal
  xcol_s1<<<dim3(4, 64), dim3(256), 0, stream>>>((const float2*)x, X1b, scal);
  xcol_s2<<<dim3(4, 64), dim3(256), 0, stream>>>(X1b, scal + 0);
  // w rotation: w @ H1 (row FWHT, bf16 out) + max
  roww_fwht<<<dim3(Kd), dim3(256), 0, stream>>>(w, W1b, scal + 1);
  // stochastic int8 quantization
  quant_x_i8<<<dim3(4096), dim3(256), 0, stream>>>(
      (const uint4*)X1b, (const float4*)noise_x, (uint2*)qx, scal);
  quant_w_t_i8<<<dim3(Kd / 64, Fd / 64), dim3(256), 0, stream>>>(
      W1b, (const float2*)noise_w, qwT, scal);
  // core i8 GEMM -> yr bf16 with fused Rl/Cl output rotation
  gemm_i8<<<dim3((Bd / 128) * (Fd / 128)), dim3(256), 0, stream>>>(qx, qwT, yr, scal);
  // remaining output stages: col-high, then row-high (+bias, f32)
  colhigh_fwht<<<dim3(Bd / 4), dim3(256), 0, stream>>>(yr);
  rowhigh_last<<<dim3(8, 64), dim3(256), 0, stream>>>((const u32*)yr, out, bias);
}